// Round 11
// baseline (90.969 us; speedup 1.0000x reference)
//
#include <hip/hip_runtime.h>

#define LL 64
#define NN 20
#define DTC 0.01f
#define NOISEC 1e-3f
#define LN2C 0.69314718056f
#define LOG2E 1.44269504089f

// R21: gt rows padded 544 -> 552 elem (1104 B, 80 mod 128): 64 lanes spread
// exactly 8 per 16B-class -> conflict-free A-reads (old 1088 B bunched 16
// lanes into 2 classes = the invariant 1.17M SQ_LDS_BANK_CONFLICT).
#define GROW 552

typedef __attribute__((ext_vector_type(8))) short short8x;
typedef __attribute__((ext_vector_type(4))) float f32x4;
typedef __attribute__((ext_vector_type(4))) int v4i;

// pack two f32 -> bf16x2 in ONE instruction (RNE) -- validated R16.
__device__ __forceinline__ unsigned cvt_pk_bf16(float x, float y) {
    unsigned r;
    asm("v_cvt_pk_bf16_f32 %0, %1, %2" : "=v"(r) : "v"(x), "v"(y));
    return r;
}

// Single-step row_shr:D (D=1..15), bound_ctrl zero-fill, applied to all 4
// dwords of a bf16x8 fragment. Bv[d](nh,qd) = Bv[0](nh-d,qd), 0 for nh<d.
template<int CTRL>
__device__ __forceinline__ short8x dpp_shr(short8x v) {
    v4i p = __builtin_bit_cast(v4i, v);
    v4i q;
    q.x = __builtin_amdgcn_update_dpp(0, p.x, CTRL, 0xf, 0xf, true);
    q.y = __builtin_amdgcn_update_dpp(0, p.y, CTRL, 0xf, 0xf, true);
    q.z = __builtin_amdgcn_update_dpp(0, p.z, CTRL, 0xf, 0xf, true);
    q.w = __builtin_amdgcn_update_dpp(0, p.w, CTRL, 0xf, 0xf, true);
    return __builtin_bit_cast(short8x, q);
}

#define DPP_EXPAND(B)                         \
    B[1]  = dpp_shr<0x111>(B[0]);             \
    B[2]  = dpp_shr<0x112>(B[0]);             \
    B[3]  = dpp_shr<0x113>(B[0]);             \
    B[4]  = dpp_shr<0x114>(B[0]);             \
    B[5]  = dpp_shr<0x115>(B[0]);             \
    B[6]  = dpp_shr<0x116>(B[0]);             \
    B[7]  = dpp_shr<0x117>(B[0]);             \
    B[8]  = dpp_shr<0x118>(B[0]);             \
    B[9]  = dpp_shr<0x119>(B[0]);             \
    B[10] = dpp_shr<0x11A>(B[0]);             \
    B[11] = dpp_shr<0x11B>(B[0]);             \
    B[12] = dpp_shr<0x11C>(B[0]);             \
    B[13] = dpp_shr<0x11D>(B[0]);             \
    B[14] = dpp_shr<0x11E>(B[0]);             \
    B[15] = dpp_shr<0x11F>(B[0]);

// R23: TWO channels per wave (512 blocks). Ledger says per-wave exposed
// stalls dominate (no pipe >50%; R13 +waves neutral, R15/R17 reorder
// neutral, R16 -VALU won, R14/R20 +VALU lost): each wave owned exactly ONE
// serial dependency chain, so its stalls (B-read wait, 8-deep MFMA chains,
// write->read turnaround, bpermute waits) had no filler. Pairing channels
// c and c+512 (same pathloss row l -> shared prep/dg/dsum/P2) gives every
// stall of chain 0 independent ops from chain 1 and vice versa. Per-CU op
// totals (DS/VALU/MFMA) are IDENTICAL to R16 -- only stall coverage changes.
// Source interleave: B0+B1 reads -> DPP0 -> A0 reads -> fill_g x2 (VALU
// covers A0 drain) -> A1 reads (drain under MFMA0) -> MFMA0/write0 ->
// DPP1 -> MFMA1/write1.
// Block-Toeplitz MFMA (validated R8/R9): Qn[32I+i] = sum_d sum_k
// G_d[i][k]*Qsrc[32(I-d)+k], G_d[i][k] = g(32d+i-k), g = DT*q_n reversed,
// zero for negative arg. gt copy kk pos w holds r[w+kk] so every A-read is
// one aligned ds_read_b128; DPP bound_ctrl zeros give the B boundary.
__global__ __launch_bounds__(64, 1) void outage_kernel(
    const float* __restrict__ pathloss,
    const float* __restrict__ powers,
    float* __restrict__ out)
{
    __shared__ __align__(16) unsigned short gt[2][2][8][GROW];  // [ch][buf]
    __shared__ __align__(16) unsigned short Qb[2][2][1024];     // [ch][buf]; [0,512)=zeros

    const int lane = threadIdx.x;
    const int c0 = blockIdx.x, b0 = c0 >> 6, l = c0 & 63;
    const int b1 = b0 + 8;             // channel 1 = c0 + 512 (same l)
    const int nh = lane & 15;          // MFMA m / n index
    const int qd = lane >> 4;          // MFMA quad (k-group)

    // ---- prep shared by both channels (same pathloss row l) ----
    const float pl = pathloss[l * LL + lane];
    float rs = pl;
    #pragma unroll
    for (int mk = 1; mk < 64; mk <<= 1) rs += __shfl_xor(rs, mk, 64);
    const float dg   = __shfl(pl, l, 64);
    const float dsum = rs - dg;

    // per-lane time constants, tau = 8*lane + u:
    //   P2[u] = 2^(tau*DT);  P1L[u] = (1-P2[u])*log2e  (exp(-(P2-1)s)==exp2(P1L*s))
    float P2[8], P1L[8];
    #pragma unroll
    for (int u = 0; u < 8; ++u) {
        float e = __builtin_amdgcn_exp2f((8 * lane + u) * DTC);
        P2[u]  = e;
        P1L[u] = (1.f - e) * LOG2E;
    }

    // zero all 4 Q prefixes (1 KiB each) and all 4 gt tails [512,544)
    *((uint4*)&Qb[0][0][0] + lane) = uint4{0u, 0u, 0u, 0u};
    *((uint4*)&Qb[0][1][0] + lane) = uint4{0u, 0u, 0u, 0u};
    *((uint4*)&Qb[1][0][0] + lane) = uint4{0u, 0u, 0u, 0u};
    *((uint4*)&Qb[1][1][0] + lane) = uint4{0u, 0u, 0u, 0u};
    {
        const int bb = lane >> 5, w = lane & 31;
        #pragma unroll
        for (int k = 0; k < 8; ++k) { gt[0][bb][k][512 + w] = 0; gt[1][bb][k][512 + w] = 0; }
    }

    // Q0(tau) = 1 - exp2(P1L*s0) per channel, bf16 into Qb[ch][0]
    const float p00 = powers[(b0 * NN + 0) * LL + l];
    const float p01 = powers[(b1 * NN + 0) * LL + l];
    const float s00 = dg * p00 / (p00 * dsum + NOISEC);
    const float s01 = dg * p01 / (p01 * dsum + NOISEC);
    float q70, q71;
    {
        float v[8], w[8];
        #pragma unroll
        for (int u = 0; u < 8; ++u) {
            v[u] = 1.f - __builtin_amdgcn_exp2f(P1L[u] * s00);
            w[u] = 1.f - __builtin_amdgcn_exp2f(P1L[u] * s01);
        }
        q70 = v[7]; q71 = w[7];                     // lane 63: Q0[511]
        uint4 d0 = { cvt_pk_bf16(v[0], v[1]), cvt_pk_bf16(v[2], v[3]),
                     cvt_pk_bf16(v[4], v[5]), cvt_pk_bf16(v[6], v[7]) };
        uint4 d1 = { cvt_pk_bf16(w[0], w[1]), cvt_pk_bf16(w[2], w[3]),
                     cvt_pk_bf16(w[4], w[5]), cvt_pk_bf16(w[6], w[7]) };
        *(uint4*)&Qb[0][0][512 + 8 * lane] = d0;
        *(uint4*)&Qb[1][0][512 + 8 * lane] = d1;
    }

    const float p1v0 = powers[(b0 * NN + 1) * LL + l];
    const float p1v1 = powers[(b1 * NN + 1) * LL + l];
    float loss0 = 1.f + p00 + (p1v0 + 1.f) * q70;   // only lane 63's is used
    float loss1 = 1.f + p01 + (p1v1 + 1.f) * q71;

    // fill the 8 shifted copies of r[tau] = DT*q_n(tau) into table gtb
    // (R16-proven: shfl_down neighbor pairs + alignbit E-pairs)
    auto fill_g = [&](unsigned short* gtb, float p) {
        float s  = dg * p / (p * dsum + NOISEC);
        float cm = s * LN2C * DTC;
        unsigned F[8];                               // F[0..3] own pairs, F[4..7] neighbor
        #pragma unroll
        for (int w = 0; w < 4; ++w) {
            float a  = __builtin_amdgcn_exp2f(P1L[2 * w]     * s) * (P2[2 * w]     * cm);
            float bb = __builtin_amdgcn_exp2f(P1L[2 * w + 1] * s) * (P2[2 * w + 1] * cm);
            F[w] = cvt_pk_bf16(a, bb);
        }
        #pragma unroll
        for (int w = 0; w < 4; ++w) {
            unsigned t = (unsigned)__shfl_down((int)F[w], 1, 64);
            F[4 + w] = (lane == 63) ? 0u : t;       // tau >= 512 -> 0
        }
        unsigned E[7];                               // odd-phase pairs: 1 alignbit each
        #pragma unroll
        for (int j = 0; j < 7; ++j) E[j] = __builtin_amdgcn_alignbit(F[j + 1], F[j], 16);
        #pragma unroll
        for (int k = 0; k < 8; ++k) {               // copy k pos 8L+w holds r[8L+w+k]
            uint4 d4;
            if ((k & 1) == 0) d4 = uint4{F[k / 2], F[k / 2 + 1], F[k / 2 + 2], F[k / 2 + 3]};
            else              d4 = uint4{E[k / 2], E[k / 2 + 1], E[k / 2 + 2], E[k / 2 + 3]};
            *(uint4*)&gtb[k * GROW + 8 * lane] = d4;
        }
    };
    fill_g(&gt[0][1][0][0], p1v0);                  // g-tables for step n=1
    fill_g(&gt[1][1][0][0], p1v1);

    const int kk    = (7 - nh) & 7;                 // this lane's copy index
    const int baseA = 511 - nh + 8 * qd - kk;       // == 0 mod 8 (16B aligned)
    const int baseB = 512 + 32 * nh + 8 * qd;
    const int dstw  = 512 + 32 * nh + 4 * qd;       // +16 for M-tile 1

    float pn0 = powers[(b0 * NN + 2) * LL + l];     // pw[n+1] entering n=1
    float pn1 = powers[(b1 * NN + 2) * LL + l];

    for (int n = 1; n < NN; ++n) {
        const int bufO = (n + 1) & 1, bufN = n & 1;
        const unsigned short* psrc0 = &Qb[0][bufO][0];
        const unsigned short* psrc1 = &Qb[1][bufO][0];
        const unsigned short* pg0   = &gt[0][bufN][kk][0];
        const unsigned short* pg1   = &gt[1][bufN][kk][0];
        unsigned short* pdst0       = &Qb[0][bufN][0];
        unsigned short* pdst1       = &Qb[1][bufN][0];

        // next-next power loads (land during this step's work)
        float pf0 = 0.f, pf1 = 0.f;
        if (n <= NN - 3) {
            pf0 = powers[(b0 * NN + n + 2) * LL + l];
            pf1 = powers[(b1 * NN + n + 2) * LL + l];
        }

        // ---- both B-fragment reads, then ch0's DPP expansion ----
        short8x B0[16], B1[16];
        B0[0] = *(const short8x*)&psrc0[baseB];
        B1[0] = *(const short8x*)&psrc1[baseB];
        DPP_EXPAND(B0)

        // ---- A operands ch0 (32 x ds_read_b128, bank-balanced) ----
        short8x A00[16], A01[16];
        #pragma unroll
        for (int d = 0; d < 16; ++d) {
            A00[d] = *(const short8x*)&pg0[baseA - 32 * d];
            A01[d] = *(const short8x*)&pg0[baseA - 32 * d - 16];
        }

        // ---- g-tables for step n+1, both channels (VALU covers A0 drain) ----
        if (n < NN - 1) {
            fill_g(&gt[0][bufO][0][0], pn0);
            fill_g(&gt[1][bufO][0][0], pn1);
        }

        // ---- A operands ch1 (drain under MFMA0 below) ----
        short8x A10[16], A11[16];
        #pragma unroll
        for (int d = 0; d < 16; ++d) {
            A10[d] = *(const short8x*)&pg1[baseA - 32 * d];
            A11[d] = *(const short8x*)&pg1[baseA - 32 * d - 16];
        }

        // ---- MFMA chains ch0 (4 independent, depth 8) ----
        f32x4 c0a = {0.f,0.f,0.f,0.f}, c0b = {0.f,0.f,0.f,0.f};
        f32x4 c1a = {0.f,0.f,0.f,0.f}, c1b = {0.f,0.f,0.f,0.f};
        #pragma unroll
        for (int d = 0; d < 16; d += 2) {
            c0a = __builtin_amdgcn_mfma_f32_16x16x32_bf16(A00[d],     B0[d],     c0a, 0, 0, 0);
            c1a = __builtin_amdgcn_mfma_f32_16x16x32_bf16(A01[d],     B0[d],     c1a, 0, 0, 0);
            c0b = __builtin_amdgcn_mfma_f32_16x16x32_bf16(A00[d + 1], B0[d + 1], c0b, 0, 0, 0);
            c1b = __builtin_amdgcn_mfma_f32_16x16x32_bf16(A01[d + 1], B0[d + 1], c1b, 0, 0, 0);
        }
        f32x4 acc00 = c0a + c0b;
        f32x4 acc01 = c1a + c1b;
        *(uint2*)&pdst0[dstw]      = uint2{cvt_pk_bf16(acc00.x, acc00.y), cvt_pk_bf16(acc00.z, acc00.w)};
        *(uint2*)&pdst0[dstw + 16] = uint2{cvt_pk_bf16(acc01.x, acc01.y), cvt_pk_bf16(acc01.z, acc01.w)};

        // ---- ch1: DPP expansion + MFMA chains ----
        DPP_EXPAND(B1)
        f32x4 d0a = {0.f,0.f,0.f,0.f}, d0b = {0.f,0.f,0.f,0.f};
        f32x4 d1a = {0.f,0.f,0.f,0.f}, d1b = {0.f,0.f,0.f,0.f};
        #pragma unroll
        for (int d = 0; d < 16; d += 2) {
            d0a = __builtin_amdgcn_mfma_f32_16x16x32_bf16(A10[d],     B1[d],     d0a, 0, 0, 0);
            d1a = __builtin_amdgcn_mfma_f32_16x16x32_bf16(A11[d],     B1[d],     d1a, 0, 0, 0);
            d0b = __builtin_amdgcn_mfma_f32_16x16x32_bf16(A10[d + 1], B1[d + 1], d0b, 0, 0, 0);
            d1b = __builtin_amdgcn_mfma_f32_16x16x32_bf16(A11[d + 1], B1[d + 1], d1b, 0, 0, 0);
        }
        f32x4 acc10 = d0a + d0b;
        f32x4 acc11 = d1a + d1b;
        *(uint2*)&pdst1[dstw]      = uint2{cvt_pk_bf16(acc10.x, acc10.y), cvt_pk_bf16(acc10.z, acc10.w)};
        *(uint2*)&pdst1[dstw + 16] = uint2{cvt_pk_bf16(acc11.x, acc11.y), cvt_pk_bf16(acc11.z, acc11.w)};

        // loss taps: lane 63 acc?1.w == Qn[511] (row 31, col 15), fp32
        float w0 = (n < NN - 1) ? (pn0 + 1.f) : 1.f;   // pn == pw[n+1]
        float w1 = (n < NN - 1) ? (pn1 + 1.f) : 1.f;
        loss0 += w0 * acc01.w;
        loss1 += w1 * acc11.w;
        pn0 = pf0; pn1 = pf1;
    }

    if (lane == 63) atomicAdd(out, loss0 + loss1);
}

extern "C" void kernel_launch(void* const* d_in, const int* in_sizes, int n_in,
                              void* d_out, int out_size, void* d_ws, size_t ws_size,
                              hipStream_t stream) {
    const float* pathloss = (const float*)d_in[0];
    const float* powers   = (const float*)d_in[1];
    float* outp = (float*)d_out;

    (void)hipMemsetAsync(d_out, 0, sizeof(float) * out_size, stream);
    outage_kernel<<<8 * LL, 64, 0, stream>>>(pathloss, powers, outp);
}